// Round 2
// baseline (251.767 us; speedup 1.0000x reference)
//
#include <hip/hip_runtime.h>
#include <hip/hip_bf16.h>
#include <stdint.h>

#define B_ 8
#define N_ 2048
#define F_ 64
#define FH_ 64
#define H_ 4
#define C_ (H_*FH_)
#define CHUNK 64
#define NCHUNK (N_/CHUNK)
#define LOG2E 1.44269504088896340736f

typedef short short8 __attribute__((ext_vector_type(8)));   // 8 bf16 raw bits (4 VGPRs)
typedef float f32x4 __attribute__((ext_vector_type(4)));

// float -> bf16 raw bits (RNE)
__device__ __forceinline__ short f2bf(float f) {
    __hip_bfloat16 h = __float2bfloat16(f);
    return __builtin_bit_cast(short, h);
}

// async global->LDS DMA (the only prefetch the compiler cannot sink: R7-R11)
__device__ __forceinline__ void async16(void* l, const void* g) {
    __builtin_amdgcn_global_load_lds((const __attribute__((address_space(1))) unsigned int*)g,
                                     (__attribute__((address_space(3))) unsigned int*)l, 16, 0, 0);
}
__device__ __forceinline__ void async4(void* l, const void* g) {
    __builtin_amdgcn_global_load_lds((const __attribute__((address_space(1))) unsigned int*)g,
                                     (__attribute__((address_space(3))) unsigned int*)l, 4, 0, 0);
}

// ---------------- KF: fused [k1 feats+scores | kp mask-pack] ----------------
// Blocks [0,1024): k1 (featsT + ss/sn, W transposed in-LDS -- k0 eliminated).
// Blocks [1024,5120): kp (A -> 1-bit mask). The two parts are independent; fusing
// them lets the ~21 us HBM-bound A read overlap the ~15 us k1 instead of serializing.
__global__ __launch_bounds__(256) void kf(const float* __restrict__ A,
                                          const float* __restrict__ X,
                                          const float* __restrict__ W,
                                          const float* __restrict__ a_self,
                                          const float* __restrict__ a_neigh,
                                          unsigned long long* __restrict__ Amask,
                                          __hip_bfloat16* __restrict__ featsT,
                                          float* __restrict__ ss,
                                          float* __restrict__ sn) {
    __shared__ float a_lds[2][FH_];
    __shared__ __hip_bfloat16 cw_lds[FH_ * 72];    // W^T (bf16) during MFMA, then C
    const int bx = blockIdx.x;
    const int tid = threadIdx.x;
    const int wave = tid >> 6, lane = tid & 63;

    if (bx >= 1024) {
        // ---------------- kp part ----------------
        const int R = (bx - 1024) * 4 + wave;      // global row 0..16383 (= b*N + i)
        const float* arow = A + (size_t)R * N_;
        unsigned long long* mrow = Amask + (size_t)R * (N_ / 64);
#pragma unroll
        for (int i = 0; i < 8; ++i) {              // 8 x 256 cols
            float a0 = arow[i * 256 + lane];
            float a1 = arow[i * 256 + 64 + lane];
            float a2 = arow[i * 256 + 128 + lane];
            float a3 = arow[i * 256 + 192 + lane];
            unsigned long long m0 = __ballot(a0 != 0.0f);
            unsigned long long m1 = __ballot(a1 != 0.0f);
            unsigned long long m2 = __ballot(a2 != 0.0f);
            unsigned long long m3 = __ballot(a3 != 0.0f);
            if (lane == 0) {
                mrow[i * 4 + 0] = m0; mrow[i * 4 + 1] = m1;
                mrow[i * 4 + 2] = m2; mrow[i * 4 + 3] = m3;
            }
        }
        return;
    }

    // ---------------- k1 part ----------------
    const int nb = bx & 31, h = (bx >> 5) & 3, b = bx >> 7;

    if (tid < 64)       a_lds[0][tid] = a_self[h * FH_ + tid];
    else if (tid < 128) a_lds[1][tid - 64] = a_neigh[h * FH_ + tid - 64];
    {   // stage W[h] transposed to bf16: cw_lds[o*72+f] = bf16(W[h][f][o])
        int f = tid >> 2, o0 = (tid & 3) * 16;
        const float* wsrc = W + ((size_t)(h * F_ + f)) * FH_ + o0;
#pragma unroll
        for (int k = 0; k < 16; ++k)
            cw_lds[(o0 + k) * 72 + f] = __float2bfloat16(wsrc[k]);
    }
    __syncthreads();

    const int m = lane & 15, q = lane >> 4;
    const int nl = wave * 16 + m;               // local column 0..63
    const int n = nb * 64 + nl;                 // B-frag column (node index)
    f32x4 acc[4] = {};
#pragma unroll
    for (int ks = 0; ks < 2; ++ks) {            // K = F = 64, two steps of 32
        const float* xp = X + ((size_t)(b * N_ + n)) * F_ + ks * 32 + q * 8;
        float4 x0 = *(const float4*)xp;
        float4 x1 = *(const float4*)(xp + 4);
        short8 bfrag;
        bfrag[0] = f2bf(x0.x); bfrag[1] = f2bf(x0.y);
        bfrag[2] = f2bf(x0.z); bfrag[3] = f2bf(x0.w);
        bfrag[4] = f2bf(x1.x); bfrag[5] = f2bf(x1.y);
        bfrag[6] = f2bf(x1.z); bfrag[7] = f2bf(x1.w);
#pragma unroll
        for (int ot = 0; ot < 4; ++ot) {
            short8 afrag = *(const short8*)(cw_lds + (ot * 16 + m) * 72 + ks * 32 + q * 8);
            acc[ot] = __builtin_amdgcn_mfma_f32_16x16x32_bf16(afrag, bfrag, acc[ot], 0, 0, 0);
        }
    }
    __syncthreads();    // all W reads done before C overwrites the buffer
    float ssv = 0.f, snv = 0.f;
#pragma unroll
    for (int ot = 0; ot < 4; ++ot) {
#pragma unroll
        for (int r = 0; r < 4; ++r) {
            int orow = ot * 16 + q * 4 + r;     // C: row=(lane>>4)*4+r, col=lane&15
            float v = acc[ot][r];
            cw_lds[orow * 72 + nl] = __float2bfloat16(v);
            ssv += v * a_lds[0][orow];
            snv += v * a_lds[1][orow];
        }
    }
    ssv += __shfl_xor(ssv, 16); ssv += __shfl_xor(ssv, 32);
    snv += __shfl_xor(snv, 16); snv += __shfl_xor(snv, 32);
    __syncthreads();
    {   // coalesced featsT store: thread t -> feature o = t>>2, 16-col chunk (t&3)
        int o = tid >> 2, c = (tid & 3) * 16;
        const __hip_bfloat16* src = cw_lds + o * 72 + c;
        __hip_bfloat16* dst = featsT + ((size_t)(b * H_ + h) * FH_ + o) * N_ + nb * 64 + c;
        *(uint4*)dst       = *(const uint4*)src;
        *(uint4*)(dst + 8) = *(const uint4*)(src + 8);
    }
    if (lane < 16) {
        size_t idx = ((size_t)(b * H_ + h)) * N_ + n;
        ss[idx] = ssv * LOG2E;
        sn[idx] = snv * LOG2E;
    }
}

// ---------------- K3: DMA-pipelined fused softmax+PV (R12 verbatim) ----------------
// grid (N/64, H, B) = 1024 blocks = 4/CU; block = 1 head, 64 rows; wave owns 16 rows.
// K-loop: 32 chunks of 64 cols; fv chunk (8 KB, XOR-swizzled) + mask chunk (512 B)
// DMA-staged double-buffered; one __syncthreads per chunk; inner loop reads LDS only.
// (R13/R14 drain-free/sched_barrier variants measured SLOWER -- keep this shape.)
__global__ __launch_bounds__(256, 4) void k3_attn(const unsigned int* __restrict__ Amask,
                                                  const __hip_bfloat16* __restrict__ featsT,
                                                  const float* __restrict__ ss,
                                                  const float* __restrict__ sn,
                                                  const float* __restrict__ bias,
                                                  float* __restrict__ out) {
    __shared__ __hip_bfloat16 fv_lds[2][64 * CHUNK];   // 2 x 8 KB, swizzled
    __shared__ unsigned int   mk_lds[2][64 * 2];       // 2 x 512 B
    __shared__ float e1_lds[N_];                       // 8 KB: 2^sn_j
    __shared__ float e2_lds[N_];                       // 8 KB: 2^(0.2 sn_j)

    const int tile = blockIdx.x, h = blockIdx.y, b = blockIdx.z;
    const int tid = threadIdx.x, wave = tid >> 6, lane = tid & 63;
    const int m = lane & 15, q = lane >> 4;
    const int rowtile = tile * 64;

    {   // e-tables: 512 float4 slots, 2 per thread
        const float4* snrow = (const float4*)(sn + ((size_t)(b * H_ + h)) * N_);
        float4* e1v = (float4*)e1_lds;
        float4* e2v = (float4*)e2_lds;
#pragma unroll
        for (int i = 0; i < 2; ++i) {
            int idx = tid + i * 256;
            float4 v = snrow[idx];
            float4 u1, u2;
            u1.x = exp2f(v.x); u1.y = exp2f(v.y); u1.z = exp2f(v.z); u1.w = exp2f(v.w);
            u2.x = exp2f(0.2f * v.x); u2.y = exp2f(0.2f * v.y);
            u2.z = exp2f(0.2f * v.z); u2.w = exp2f(0.2f * v.w);
            e1v[idx] = u1; e2v[idx] = u2;
        }
    }
    const float ssi = ss[((size_t)(b * H_ + h)) * N_ + rowtile + wave * 16 + m];
    const float e1i = exp2f(ssi), e2i = exp2f(0.2f * ssi);

    const __hip_bfloat16* fhead = featsT + ((size_t)(b * H_ + h)) * FH_ * N_;
    const unsigned int* mbase = Amask + ((size_t)(b * N_) + rowtile) * (N_ / 32);

    // stage chunk c into buffer bufi (wave-uniform LDS base + lane*size per HW contract)
    auto stage = [&](int c, int bufi) {
        const int cb = c * CHUNK;
#pragma unroll
        for (int i = 0; i < 2; ++i) {           // fv: 64 feats x 64 cols, 512 16B-units
            int base_unit = i * 256 + wave * 64;
            int unit = base_unit + lane;
            int o = unit >> 3, v = unit & 7;
            int u = v ^ (o & 7);                // XOR swizzle (compute-side conflict-free)
            async16(&fv_lds[bufi][base_unit * 8], fhead + (size_t)o * N_ + cb + u * 8);
        }
        if (wave < 2) {                         // mask: 64 rows x 2 dwords = 128 units
            int base_unit = wave * 64;
            int unit = base_unit + lane;
            int row = unit >> 1, dw = unit & 1;
            async4(&mk_lds[bufi][base_unit], mbase + (size_t)row * (N_ / 32) + (cb >> 5) + dw);
        }
    };

    stage(0, 0);
    __syncthreads();    // drains DMA (vmcnt) + e-table LDS writes

    f32x4 acc[2][4] = {};       // [chain][ct]
    f32x4 accl[2] = {};
    short8 ones;
#pragma unroll
    for (int s = 0; s < 8; ++s) ones[s] = (short)0x3F80;   // bf16 1.0

    for (int c = 0; c < NCHUNK; ++c) {
        const int cur = c & 1;
        if (c + 1 < NCHUNK) stage(c + 1, cur ^ 1);

        const int cg = c * CHUNK;
        // e-tables (broadcast within q-group -> near-free LDS reads)
        float4 eA10 = *(const float4*)(e1_lds + cg + q * 8);
        float4 eA11 = *(const float4*)(e1_lds + cg + q * 8 + 4);
        float4 eB10 = *(const float4*)(e1_lds + cg + 32 + q * 8);
        float4 eB11 = *(const float4*)(e1_lds + cg + 32 + q * 8 + 4);
        float4 eA20 = *(const float4*)(e2_lds + cg + q * 8);
        float4 eA21 = *(const float4*)(e2_lds + cg + q * 8 + 4);
        float4 eB20 = *(const float4*)(e2_lds + cg + 32 + q * 8);
        float4 eB21 = *(const float4*)(e2_lds + cg + 32 + q * 8 + 4);
        // fv fragments: chain A = col-units 0..3 (uA=q), chain B = units 4..7
        short8 fA[4], fB[4];
#pragma unroll
        for (int ct = 0; ct < 4; ++ct) {
            int o = ct * 16 + m;
            fA[ct] = *(const short8*)(fv_lds[cur] + ((o << 3) + (q ^ (o & 7))) * 8);
            fB[ct] = *(const short8*)(fv_lds[cur] + ((o << 3) + ((4 + q) ^ (o & 7))) * 8);
        }
        // mask dwords for this row (broadcast within q-group)
        unsigned int mA = mk_lds[cur][(wave * 16 + m) * 2];
        unsigned int mB = mk_lds[cur][(wave * 16 + m) * 2 + 1];

        float e1A[8] = {eA10.x, eA10.y, eA10.z, eA10.w, eA11.x, eA11.y, eA11.z, eA11.w};
        float e1B[8] = {eB10.x, eB10.y, eB10.z, eB10.w, eB11.x, eB11.y, eB11.z, eB11.w};
        float e2A[8] = {eA20.x, eA20.y, eA20.z, eA20.w, eA21.x, eA21.y, eA21.z, eA21.w};
        float e2B[8] = {eB20.x, eB20.y, eB20.z, eB20.w, eB21.x, eB21.y, eB21.z, eB21.w};

        short8 pA, pB;
#pragma unroll
        for (int s = 0; s < 8; ++s) {
            // exp2(leaky(si+sj)) = max(e1i*e1j, e2i*e2j); adjacency via bit test
            float vA = fmaxf(e1i * e1A[s], e2i * e2A[s]);
            float vB = fmaxf(e1i * e1B[s], e2i * e2B[s]);
            const int bit = q * 8 + s;
            pA[s] = (mA >> bit) & 1 ? f2bf(vA) : (short)0;
            pB[s] = (mB >> bit) & 1 ? f2bf(vB) : (short)0;
        }
#pragma unroll
        for (int ct = 0; ct < 4; ++ct) {
            acc[0][ct] = __builtin_amdgcn_mfma_f32_16x16x32_bf16(pA, fA[ct], acc[0][ct], 0, 0, 0);
            acc[1][ct] = __builtin_amdgcn_mfma_f32_16x16x32_bf16(pB, fB[ct], acc[1][ct], 0, 0, 0);
        }
        accl[0] = __builtin_amdgcn_mfma_f32_16x16x32_bf16(pA, ones, accl[0], 0, 0, 0);
        accl[1] = __builtin_amdgcn_mfma_f32_16x16x32_bf16(pB, ones, accl[1], 0, 0, 0);

        __syncthreads();    // drain next-chunk DMA; release cur buffer
    }

    float bc[4];
#pragma unroll
    for (int ct = 0; ct < 4; ++ct) bc[ct] = bias[h * FH_ + ct * 16 + m];

#pragma unroll
    for (int r = 0; r < 4; ++r) {
        float inv = 1.0f / (accl[0][r] + accl[1][r]);   // row sum (all cols identical)
        int gr = rowtile + wave * 16 + q * 4 + r;
#pragma unroll
        for (int ct = 0; ct < 4; ++ct) {
            float v = (acc[0][ct][r] + acc[1][ct][r]) * inv + bc[ct];
            out[((size_t)(b * N_) + gr) * C_ + h * FH_ + ct * 16 + m] = fmaxf(v, 0.0f);
        }
    }
}

extern "C" void kernel_launch(void* const* d_in, const int* in_sizes, int n_in,
                              void* d_out, int out_size, void* d_ws, size_t ws_size,
                              hipStream_t stream) {
    const float* X       = (const float*)d_in[0];
    const float* A       = (const float*)d_in[1];
    const float* W       = (const float*)d_in[2];
    const float* bias    = (const float*)d_in[3];
    const float* a_self  = (const float*)d_in[4];
    const float* a_neigh = (const float*)d_in[5];
    float* out = (float*)d_out;   // reference output dtype is float32

    char* ws = (char*)d_ws;
    __hip_bfloat16* featsT = (__hip_bfloat16*)(ws);             // 8 MB   [B][H][FH][N]
    float* ss              = (float*)(ws + 8421376);            // 256 KB [B][H][N]
    float* sn              = (float*)(ws + 8683520);            // 256 KB [B][H][N]
    unsigned long long* Am = (unsigned long long*)(ws + 8945664); // 4 MB bitmask

    kf      <<<5120, 256, 0, stream>>>(A, X, W, a_self, a_neigh, Am, featsT, ss, sn);
    k3_attn <<<dim3(N_ / 64, H_, B_), 256, 0, stream>>>((const unsigned int*)Am, featsT, ss, sn, bias, out);
}

// Round 3
// 249.514 us; speedup vs baseline: 1.0090x; 1.0090x over previous
//
#include <hip/hip_runtime.h>
#include <hip/hip_bf16.h>
#include <stdint.h>

#define B_ 8
#define N_ 2048
#define F_ 64
#define FH_ 64
#define H_ 4
#define C_ (H_*FH_)
#define CHUNK 64
#define NCHUNK (N_/CHUNK)
#define LOG2E 1.44269504088896340736f

typedef short short8 __attribute__((ext_vector_type(8)));   // 8 bf16 raw bits (4 VGPRs)
typedef float f32x4 __attribute__((ext_vector_type(4)));

// float -> bf16 raw bits (RNE)
__device__ __forceinline__ short f2bf(float f) {
    __hip_bfloat16 h = __float2bfloat16(f);
    return __builtin_bit_cast(short, h);
}

// async global->LDS DMA (the only prefetch the compiler cannot sink: R7-R11)
__device__ __forceinline__ void async16(void* l, const void* g) {
    __builtin_amdgcn_global_load_lds((const __attribute__((address_space(1))) unsigned int*)g,
                                     (__attribute__((address_space(3))) unsigned int*)l, 16, 0, 0);
}

// ---------------- KF: fused [k1 feats+scores | kp mask-pack] ----------------
// Blocks [0,1024): k1 (featsT + ss/sn, W transposed in-LDS -- k0 eliminated).
// Blocks [1024,5120): kp (A -> 1-bit mask). The two parts are independent; fusing
// them lets the ~19 us HBM-bound A read overlap the k1 MFMA work.
// (R2 profile: fills hit 6.9 TB/s on this box; A-read floor ~19 us.)
__global__ __launch_bounds__(256) void kf(const float* __restrict__ A,
                                          const float* __restrict__ X,
                                          const float* __restrict__ W,
                                          const float* __restrict__ a_self,
                                          const float* __restrict__ a_neigh,
                                          unsigned long long* __restrict__ Amask,
                                          __hip_bfloat16* __restrict__ featsT,
                                          float* __restrict__ ss,
                                          float* __restrict__ sn) {
    __shared__ float a_lds[2][FH_];
    __shared__ __hip_bfloat16 cw_lds[FH_ * 72];    // W^T (bf16) during MFMA, then C
    const int bx = blockIdx.x;
    const int tid = threadIdx.x;
    const int wave = tid >> 6, lane = tid & 63;

    if (bx >= 1024) {
        // ---------------- kp part ----------------
        const int R = (bx - 1024) * 4 + wave;      // global row 0..16383 (= b*N + i)
        const float* arow = A + (size_t)R * N_;
        unsigned long long* mrow = Amask + (size_t)R * (N_ / 64);
#pragma unroll
        for (int i = 0; i < 8; ++i) {              // 8 x 256 cols
            float a0 = arow[i * 256 + lane];
            float a1 = arow[i * 256 + 64 + lane];
            float a2 = arow[i * 256 + 128 + lane];
            float a3 = arow[i * 256 + 192 + lane];
            unsigned long long m0 = __ballot(a0 != 0.0f);
            unsigned long long m1 = __ballot(a1 != 0.0f);
            unsigned long long m2 = __ballot(a2 != 0.0f);
            unsigned long long m3 = __ballot(a3 != 0.0f);
            if (lane == 0) {
                mrow[i * 4 + 0] = m0; mrow[i * 4 + 1] = m1;
                mrow[i * 4 + 2] = m2; mrow[i * 4 + 3] = m3;
            }
        }
        return;
    }

    // ---------------- k1 part ----------------
    const int nb = bx & 31, h = (bx >> 5) & 3, b = bx >> 7;

    if (tid < 64)       a_lds[0][tid] = a_self[h * FH_ + tid];
    else if (tid < 128) a_lds[1][tid - 64] = a_neigh[h * FH_ + tid - 64];
    {   // stage W[h] transposed to bf16: cw_lds[o*72+f] = bf16(W[h][f][o])
        int f = tid >> 2, o0 = (tid & 3) * 16;
        const float* wsrc = W + ((size_t)(h * F_ + f)) * FH_ + o0;
#pragma unroll
        for (int k = 0; k < 16; ++k)
            cw_lds[(o0 + k) * 72 + f] = __float2bfloat16(wsrc[k]);
    }
    __syncthreads();

    const int m = lane & 15, q = lane >> 4;
    const int nl = wave * 16 + m;               // local column 0..63
    const int n = nb * 64 + nl;                 // B-frag column (node index)
    f32x4 acc[4] = {};
#pragma unroll
    for (int ks = 0; ks < 2; ++ks) {            // K = F = 64, two steps of 32
        const float* xp = X + ((size_t)(b * N_ + n)) * F_ + ks * 32 + q * 8;
        float4 x0 = *(const float4*)xp;
        float4 x1 = *(const float4*)(xp + 4);
        short8 bfrag;
        bfrag[0] = f2bf(x0.x); bfrag[1] = f2bf(x0.y);
        bfrag[2] = f2bf(x0.z); bfrag[3] = f2bf(x0.w);
        bfrag[4] = f2bf(x1.x); bfrag[5] = f2bf(x1.y);
        bfrag[6] = f2bf(x1.z); bfrag[7] = f2bf(x1.w);
#pragma unroll
        for (int ot = 0; ot < 4; ++ot) {
            short8 afrag = *(const short8*)(cw_lds + (ot * 16 + m) * 72 + ks * 32 + q * 8);
            acc[ot] = __builtin_amdgcn_mfma_f32_16x16x32_bf16(afrag, bfrag, acc[ot], 0, 0, 0);
        }
    }
    __syncthreads();    // all W reads done before C overwrites the buffer
    float ssv = 0.f, snv = 0.f;
#pragma unroll
    for (int ot = 0; ot < 4; ++ot) {
#pragma unroll
        for (int r = 0; r < 4; ++r) {
            int orow = ot * 16 + q * 4 + r;     // C: row=(lane>>4)*4+r, col=lane&15
            float v = acc[ot][r];
            cw_lds[orow * 72 + nl] = __float2bfloat16(v);
            ssv += v * a_lds[0][orow];
            snv += v * a_lds[1][orow];
        }
    }
    ssv += __shfl_xor(ssv, 16); ssv += __shfl_xor(ssv, 32);
    snv += __shfl_xor(snv, 16); snv += __shfl_xor(snv, 32);
    __syncthreads();
    {   // coalesced featsT store: thread t -> feature o = t>>2, 16-col chunk (t&3)
        int o = tid >> 2, c = (tid & 3) * 16;
        const __hip_bfloat16* src = cw_lds + o * 72 + c;
        __hip_bfloat16* dst = featsT + ((size_t)(b * H_ + h) * FH_ + o) * N_ + nb * 64 + c;
        *(uint4*)dst       = *(const uint4*)src;
        *(uint4*)(dst + 8) = *(const uint4*)(src + 8);
    }
    if (lane < 16) {
        size_t idx = ((size_t)(b * H_ + h)) * N_ + n;
        ss[idx] = ssv * LOG2E;
        sn[idx] = snv * LOG2E;
    }
}

// ---------------- K3: pipelined-P fused softmax+PV (R15) ----------------
// R2 theory: k3 was latency-bound on the post-barrier chain
// (barrier -> e-table LDS loads -> 48-op mul/max chain -> cvt -> MFMA).
// Change: masks prefetched to REGISTERS 2 chunks ahead (global dwordx2;
// the pre-barrier vmcnt drain guarantees arrival), and P for chunk c+1 is
// built DURING chunk c from static e-tables + mask regs, in-place after the
// MFMAs consume the old P. Post-barrier path is now just fv ds_reads -> MFMA.
// mk_lds / async4 deleted. Numerics bit-identical to R12.
__global__ __launch_bounds__(256, 4) void k3_attn(const unsigned int* __restrict__ Amask,
                                                  const __hip_bfloat16* __restrict__ featsT,
                                                  const float* __restrict__ ss,
                                                  const float* __restrict__ sn,
                                                  const float* __restrict__ bias,
                                                  float* __restrict__ out) {
    __shared__ __hip_bfloat16 fv_lds[2][64 * CHUNK];   // 2 x 8 KB, swizzled
    __shared__ float e1_lds[N_];                       // 8 KB: 2^sn_j
    __shared__ float e2_lds[N_];                       // 8 KB: 2^(0.2 sn_j)

    const int tile = blockIdx.x, h = blockIdx.y, b = blockIdx.z;
    const int tid = threadIdx.x, wave = tid >> 6, lane = tid & 63;
    const int m = lane & 15, q = lane >> 4;
    const int rowtile = tile * 64;

    {   // e-tables: 512 float4 slots, 2 per thread
        const float4* snrow = (const float4*)(sn + ((size_t)(b * H_ + h)) * N_);
        float4* e1v = (float4*)e1_lds;
        float4* e2v = (float4*)e2_lds;
#pragma unroll
        for (int i = 0; i < 2; ++i) {
            int idx = tid + i * 256;
            float4 v = snrow[idx];
            float4 u1, u2;
            u1.x = exp2f(v.x); u1.y = exp2f(v.y); u1.z = exp2f(v.z); u1.w = exp2f(v.w);
            u2.x = exp2f(0.2f * v.x); u2.y = exp2f(0.2f * v.y);
            u2.z = exp2f(0.2f * v.z); u2.w = exp2f(0.2f * v.w);
            e1v[idx] = u1; e2v[idx] = u2;
        }
    }
    const float ssi = ss[((size_t)(b * H_ + h)) * N_ + rowtile + wave * 16 + m];
    const float e1i = exp2f(ssi), e2i = exp2f(0.2f * ssi);

    const __hip_bfloat16* fhead = featsT + ((size_t)(b * H_ + h)) * FH_ * N_;
    // per-thread mask row pointer: row = rowtile + wave*16 + m, 2 dwords per chunk
    const unsigned int* mrow = Amask + ((size_t)(b * N_) + rowtile + wave * 16 + m) * (N_ / 32);

    // stage fv chunk c into buffer bufi (wave-uniform LDS base + lane*size per HW contract)
    auto stage = [&](int c, int bufi) {
        const int cb = c * CHUNK;
#pragma unroll
        for (int i = 0; i < 2; ++i) {           // fv: 64 feats x 64 cols, 512 16B-units
            int base_unit = i * 256 + wave * 64;
            int unit = base_unit + lane;
            int o = unit >> 3, v = unit & 7;
            int u = v ^ (o & 7);                // XOR swizzle (compute-side conflict-free)
            async16(&fv_lds[bufi][base_unit * 8], fhead + (size_t)o * N_ + cb + u * 8);
        }
    };

    // build P (pA, pB) for chunk c from static e-tables + mask registers
    auto buildP = [&](int c, unsigned int mA, unsigned int mB, short8& pA, short8& pB) {
        const int cg = c * CHUNK;
        float4 eA10 = *(const float4*)(e1_lds + cg + q * 8);
        float4 eA11 = *(const float4*)(e1_lds + cg + q * 8 + 4);
        float4 eB10 = *(const float4*)(e1_lds + cg + 32 + q * 8);
        float4 eB11 = *(const float4*)(e1_lds + cg + 32 + q * 8 + 4);
        float4 eA20 = *(const float4*)(e2_lds + cg + q * 8);
        float4 eA21 = *(const float4*)(e2_lds + cg + q * 8 + 4);
        float4 eB20 = *(const float4*)(e2_lds + cg + 32 + q * 8);
        float4 eB21 = *(const float4*)(e2_lds + cg + 32 + q * 8 + 4);
        float e1A[8] = {eA10.x, eA10.y, eA10.z, eA10.w, eA11.x, eA11.y, eA11.z, eA11.w};
        float e1B[8] = {eB10.x, eB10.y, eB10.z, eB10.w, eB11.x, eB11.y, eB11.z, eB11.w};
        float e2A[8] = {eA20.x, eA20.y, eA20.z, eA20.w, eA21.x, eA21.y, eA21.z, eA21.w};
        float e2B[8] = {eB20.x, eB20.y, eB20.z, eB20.w, eB21.x, eB21.y, eB21.z, eB21.w};
#pragma unroll
        for (int s = 0; s < 8; ++s) {
            // exp2(leaky(si+sj)) = max(e1i*e1j, e2i*e2j); adjacency via bit test
            float vA = fmaxf(e1i * e1A[s], e2i * e2A[s]);
            float vB = fmaxf(e1i * e1B[s], e2i * e2B[s]);
            const int bit = q * 8 + s;
            pA[s] = (mA >> bit) & 1 ? f2bf(vA) : (short)0;
            pB[s] = (mB >> bit) & 1 ? f2bf(vB) : (short)0;
        }
    };

    // early mask loads (latency hidden under e-table exp2 work)
    uint2 mk_use = *(const uint2*)(mrow + 0);   // chunk 0
    uint2 mk_a   = *(const uint2*)(mrow + 2);   // chunk 1

    stage(0, 0);
    __syncthreads();    // drains DMA (vmcnt -> masks also landed) + e-table LDS writes

    f32x4 acc[2][4] = {};       // [chain][ct]
    f32x4 accl[2] = {};
    short8 ones;
#pragma unroll
    for (int s = 0; s < 8; ++s) ones[s] = (short)0x3F80;   // bf16 1.0

    short8 pA, pB;
    buildP(0, mk_use.x, mk_use.y, pA, pB);

    for (int c = 0; c < NCHUNK; ++c) {
        const int cur = c & 1;
        if (c + 1 < NCHUNK) stage(c + 1, cur ^ 1);
        uint2 mk_b = mk_a;
        if (c + 2 < NCHUNK) mk_b = *(const uint2*)(mrow + (c + 2) * 2);

        // fv fragments: chain A = col-units 0..3 (uA=q), chain B = units 4..7
        short8 fA[4], fB[4];
#pragma unroll
        for (int ct = 0; ct < 4; ++ct) {
            int o = ct * 16 + m;
            fA[ct] = *(const short8*)(fv_lds[cur] + ((o << 3) + (q ^ (o & 7))) * 8);
            fB[ct] = *(const short8*)(fv_lds[cur] + ((o << 3) + ((4 + q) ^ (o & 7))) * 8);
        }
#pragma unroll
        for (int ct = 0; ct < 4; ++ct) {
            acc[0][ct] = __builtin_amdgcn_mfma_f32_16x16x32_bf16(pA, fA[ct], acc[0][ct], 0, 0, 0);
            acc[1][ct] = __builtin_amdgcn_mfma_f32_16x16x32_bf16(pB, fB[ct], acc[1][ct], 0, 0, 0);
        }
        accl[0] = __builtin_amdgcn_mfma_f32_16x16x32_bf16(pA, ones, accl[0], 0, 0, 0);
        accl[1] = __builtin_amdgcn_mfma_f32_16x16x32_bf16(pB, ones, accl[1], 0, 0, 0);

        // build P for next chunk while this chunk's DMA is in flight (in-place:
        // MFMAs above have consumed the old pA/pB)
        if (c + 1 < NCHUNK) buildP(c + 1, mk_a.x, mk_a.y, pA, pB);
        mk_a = mk_b;

        __syncthreads();    // drain next-chunk DMA; release cur buffer
    }

    float bc[4];
#pragma unroll
    for (int ct = 0; ct < 4; ++ct) bc[ct] = bias[h * FH_ + ct * 16 + m];

#pragma unroll
    for (int r = 0; r < 4; ++r) {
        float inv = 1.0f / (accl[0][r] + accl[1][r]);   // row sum (all cols identical)
        int gr = rowtile + wave * 16 + q * 4 + r;
#pragma unroll
        for (int ct = 0; ct < 4; ++ct) {
            float v = (acc[0][ct][r] + acc[1][ct][r]) * inv + bc[ct];
            out[((size_t)(b * N_) + gr) * C_ + h * FH_ + ct * 16 + m] = fmaxf(v, 0.0f);
        }
    }
}

extern "C" void kernel_launch(void* const* d_in, const int* in_sizes, int n_in,
                              void* d_out, int out_size, void* d_ws, size_t ws_size,
                              hipStream_t stream) {
    const float* X       = (const float*)d_in[0];
    const float* A       = (const float*)d_in[1];
    const float* W       = (const float*)d_in[2];
    const float* bias    = (const float*)d_in[3];
    const float* a_self  = (const float*)d_in[4];
    const float* a_neigh = (const float*)d_in[5];
    float* out = (float*)d_out;   // reference output dtype is float32

    char* ws = (char*)d_ws;
    __hip_bfloat16* featsT = (__hip_bfloat16*)(ws);             // 8 MB   [B][H][FH][N]
    float* ss              = (float*)(ws + 8421376);            // 256 KB [B][H][N]
    float* sn              = (float*)(ws + 8683520);            // 256 KB [B][H][N]
    unsigned long long* Am = (unsigned long long*)(ws + 8945664); // 4 MB bitmask

    kf      <<<5120, 256, 0, stream>>>(A, X, W, a_self, a_neigh, Am, featsT, ss, sn);
    k3_attn <<<dim3(N_ / 64, H_, B_), 256, 0, stream>>>((const unsigned int*)Am, featsT, ss, sn, bias, out);
}